// Round 17
// baseline (71.681 us; speedup 1.0000x reference)
//
#include <hip/hip_runtime.h>
#include <hip/hip_bf16.h>

#define N_ 4096
#define D_ 768
#define NCLS 128
#define BM 256
#define BN 256
#define BK 64
#define NSTEP 12  // D_/BK

typedef __bf16 bf16x8 __attribute__((ext_vector_type(8)));
typedef float f32x4 __attribute__((ext_vector_type(4)));

#define SBAR() asm volatile("s_barrier" ::: "memory")
#define VMWAIT8() asm volatile("s_waitcnt vmcnt(8)" ::: "memory")
#define LGKM0() asm volatile("s_waitcnt lgkmcnt(0)" ::: "memory")

__device__ __forceinline__ void gload16(const unsigned short* g, unsigned short* l) {
  __builtin_amdgcn_global_load_lds(
      (const __attribute__((address_space(1))) unsigned int*)g,
      (__attribute__((address_space(3))) unsigned int*)l, 16, 0, 0);
}

// Normalize both embedding matrices (blocks [0,N) -> img, [N,2N) -> txt).
// Block 0 zeroes the reduce accumulators.
__global__ __launch_bounds__(192) void normalize_kernel(
    const float* __restrict__ img, const float* __restrict__ txt,
    __hip_bfloat16* __restrict__ img_nb, __hip_bfloat16* __restrict__ txt_nb,
    double* __restrict__ accs, unsigned* __restrict__ cnt) {
  int b = blockIdx.x;
  if (b == 0 && threadIdx.x == 0) {
    accs[0] = 0.0;
    accs[1] = 0.0;
    *cnt = 0u;
  }
  const float* s;
  __hip_bfloat16* d;
  if (b < N_) {
    s = img + (size_t)b * D_;
    d = img_nb + (size_t)b * D_;
  } else {
    s = txt + (size_t)(b - N_) * D_;
    d = txt_nb + (size_t)(b - N_) * D_;
  }
  int tid = threadIdx.x;
  float4 v = ((const float4*)s)[tid];
  float ss = v.x * v.x + v.y * v.y + v.z * v.z + v.w * v.w;
#pragma unroll
  for (int m = 32; m; m >>= 1) ss += __shfl_xor(ss, m);
  __shared__ float wsum[3];
  int lane = tid & 63, w = tid >> 6;
  if (lane == 0) wsum[w] = ss;
  __syncthreads();
  float inv = 1.0f / fmaxf(sqrtf(wsum[0] + wsum[1] + wsum[2]), 1e-8f);
  ushort4 o;
  o.x = __bfloat16_as_ushort(__float2bfloat16(v.x * inv));
  o.y = __bfloat16_as_ushort(__float2bfloat16(v.y * inv));
  o.z = __bfloat16_as_ushort(__float2bfloat16(v.z * inv));
  o.w = __bfloat16_as_ushort(__float2bfloat16(v.w * inv));
  ((ushort4*)d)[tid] = o;
}

// 256x256-tile bf16 GEMM, 512 thr / 8 waves (2x4; per-wave 128x64 output,
// acc[8][4] f32x4 -- the ONLY large register array; staging is global_load_lds
// so no staging regs (r4/r5/r8's 512-thread spills all carried reg arrays).
// r16's proven machinery: pre-swizzled global source chunk=(l&7)^(row&7) ->
// linear LDS dest = conflict-free [row][chunk^row&7]; 2-slot ring, raw
// s_barrier + counted vmcnt(8); tail restages dead slot. XCD block remap.
__global__ __launch_bounds__(512) void gemm_epi_kernel(
    const unsigned short* __restrict__ A, const unsigned short* __restrict__ B,
    const int* __restrict__ labels, float* __restrict__ row_part,
    float* __restrict__ col_part, float* __restrict__ S_part) {
  __shared__ __align__(16) unsigned short As[2][16384];  // [slot][row*8+chunk][8]
  __shared__ __align__(16) unsigned short Bs[2][16384];
  __shared__ int labR[BM], labC[BN];
  __shared__ float rbuf[4][BM], cbuf[2][BN];
  __shared__ float sbuf[8];

  // XCD-aware remap (bijective; grid 256 % 8 == 0)
  const int lin = blockIdx.y * 16 + blockIdx.x;
  const int xcd = lin & 7, idx = lin >> 3;
  const int bx = xcd * 2 + (idx & 1), by = idx >> 1;

  const int tid = threadIdx.x;
  const int lane = tid & 63, wave = tid >> 6;
  const int wr = wave >> 2, wc = wave & 3;  // 2x4 wave grid
  const int g = lane >> 4, fr = lane & 15;
  const int rowBase = by * BM, colBase = bx * BN;

  if (tid < BM) labR[tid] = labels[rowBase + tid];
  else labC[tid - BM] = labels[colBase + tid - BM];
  __syncthreads();  // labels visible before any gload issue

  // staging: wave w issue j covers rows j*64 + w*8 + (lane>>3), chunk (l&7)^(row&7)
  const int r0 = lane >> 3;
  const int cswz = (lane & 7) ^ (r0 & 7);
  const unsigned short* pa = A + (size_t)(rowBase + wave * 8 + r0) * D_ + cswz * 8;
  const unsigned short* pb = B + (size_t)(colBase + wave * 8 + r0) * D_ + cswz * 8;
  const int dbase = wave * 8 * 64;  // ushort idx; + j*64*64

  // prologue: issue step 0 into slot 0 (8 loads in flight)
#pragma unroll
  for (int j = 0; j < 4; ++j) {
    gload16(pa + (size_t)(64 * j) * D_, &As[0][dbase + j * 4096]);
    gload16(pb + (size_t)(64 * j) * D_, &Bs[0][dbase + j * 4096]);
  }

  f32x4 acc[8][4] = {};

  for (int u = 0; u < NSTEP; ++u) {
    SBAR();  // all waves done reading the slot about to be overwritten
    {
      const int su = (u + 1 < NSTEP) ? u + 1 : u;  // tail: restage dead slot
      const size_t kk = (size_t)su * BK;
      const int sl = (u + 1) & 1;
#pragma unroll
      for (int j = 0; j < 4; ++j) {
        gload16(pa + (size_t)(64 * j) * D_ + kk, &As[sl][dbase + j * 4096]);
        gload16(pb + (size_t)(64 * j) * D_ + kk, &Bs[sl][dbase + j * 4096]);
      }
    }
    VMWAIT8();  // my step-u loads landed; step-u+1's 8 stay in flight
    SBAR();     // every wave's step-u loads landed: slot u&1 fully valid
    const unsigned short* as_ = As[u & 1];
    const unsigned short* bs_ = Bs[u & 1];
#pragma unroll
    for (int ks = 0; ks < 2; ++ks) {
      const int sw = (ks * 4 + g) ^ (fr & 7);
      bf16x8 bf[4];
#pragma unroll
      for (int n = 0; n < 4; ++n)
        bf[n] = *(const bf16x8*)&bs_[((wc * 64 + n * 16 + fr) * 8 + sw) * 8];
#pragma unroll
      for (int m = 0; m < 8; ++m) {
        bf16x8 af = *(const bf16x8*)&as_[((wr * 128 + m * 16 + fr) * 8 + sw) * 8];
#pragma unroll
        for (int n = 0; n < 4; ++n)
          acc[m][n] = __builtin_amdgcn_mfma_f32_16x16x32_bf16(af, bf[n], acc[m][n], 0, 0, 0);
      }
    }
    LGKM0();  // my ds_reads drained before signaling the next top barrier
  }
  __syncthreads();  // full drain before epilogue

  const float scale = 14.285714285714286f;  // 1/0.07
  float sPart = 0.f;
  float colAcc[4] = {0.f, 0.f, 0.f, 0.f};
#pragma unroll
  for (int m = 0; m < 8; ++m) {
    float ra2[4] = {0.f, 0.f, 0.f, 0.f};
#pragma unroll
    for (int n = 0; n < 4; ++n) {
      int col = wc * 64 + n * 16 + fr;
      int lc = labC[col];
#pragma unroll
      for (int r = 0; r < 4; ++r) {
        float v = acc[m][n][r] * scale;
        float e = __expf(v);
        ra2[r] += e;
        colAcc[n] += e;
        int row = wr * 128 + m * 16 + g * 4 + r;
        if (labR[row] == lc) sPart += v;
      }
    }
#pragma unroll
    for (int r = 0; r < 4; ++r) {
      float x = ra2[r];
      x += __shfl_xor(x, 1);
      x += __shfl_xor(x, 2);
      x += __shfl_xor(x, 4);
      x += __shfl_xor(x, 8);
      if (fr == 0) rbuf[wc][wr * 128 + m * 16 + g * 4 + r] = x;
    }
  }
#pragma unroll
  for (int n = 0; n < 4; ++n) {
    float x = colAcc[n];
    x += __shfl_xor(x, 16);
    x += __shfl_xor(x, 32);
    if (lane < 16) cbuf[wr][wc * 64 + n * 16 + fr] = x;
  }
  float s = sPart;
#pragma unroll
  for (int m = 32; m; m >>= 1) s += __shfl_xor(s, m);
  if (lane == 0) sbuf[wave] = s;
  __syncthreads();
  if (tid < BM) {
    row_part[(size_t)bx * N_ + rowBase + tid] =
        rbuf[0][tid] + rbuf[1][tid] + rbuf[2][tid] + rbuf[3][tid];
  } else {
    int c = tid - BM;
    col_part[(size_t)by * N_ + colBase + c] = cbuf[0][c] + cbuf[1][c];
  }
  if (tid == 0)
    S_part[by * 16 + bx] =
        sbuf[0] + sbuf[1] + sbuf[2] + sbuf[3] + sbuf[4] + sbuf[5] + sbuf[6] + sbuf[7];
}

// Merged final reduction: per-block hist + partials -> device-scope double
// atomics; last-done block writes the scalar loss.
__global__ __launch_bounds__(256) void reduce_kernel(
    const float* __restrict__ row_part, const float* __restrict__ col_part,
    const float* __restrict__ S_part, const int* __restrict__ labels,
    double* __restrict__ accs, unsigned* __restrict__ cnt, float* __restrict__ out) {
  __shared__ int hist[NCLS];
  int tid = threadIdx.x;
  if (tid < NCLS) hist[tid] = 0;
  __syncthreads();
  for (int j = tid; j < N_; j += 256) atomicAdd(&hist[labels[j]], 1);
  __syncthreads();

  int i = blockIdx.x * 256 + tid;  // 0..4095
  float rs = 0.f, cs = 0.f;
#pragma unroll
  for (int b = 0; b < 16; ++b) {
    rs += row_part[(size_t)b * N_ + i];
    cs += col_part[(size_t)b * N_ + i];
  }
  int c = hist[labels[i]];
  double term = (double)c * ((double)logf(rs) + (double)logf(cs));
  double sterm = (i < 256) ? (double)S_part[i] : 0.0;
#pragma unroll
  for (int m = 32; m; m >>= 1) {
    term += __shfl_xor(term, m);
    sterm += __shfl_xor(sterm, m);
  }
  __shared__ double tbuf[4], sb[4];
  int lane = tid & 63, w = tid >> 6;
  if (lane == 0) { tbuf[w] = term; sb[w] = sterm; }
  __syncthreads();
  if (tid == 0) {
    atomicAdd(&accs[0], tbuf[0] + tbuf[1] + tbuf[2] + tbuf[3]);
    atomicAdd(&accs[1], sb[0] + sb[1] + sb[2] + sb[3]);
    __threadfence();
    unsigned old = atomicAdd(cnt, 1u);
    if (old == 15u) {
      double t = atomicAdd(&accs[0], 0.0);
      double s2 = atomicAdd(&accs[1], 0.0);
      out[0] = (float)((t - 2.0 * s2) / (2.0 * (double)N_));
    }
  }
}

extern "C" void kernel_launch(void* const* d_in, const int* in_sizes, int n_in,
                              void* d_out, int out_size, void* d_ws, size_t ws_size,
                              hipStream_t stream) {
  const float* img = (const float*)d_in[0];
  const float* txt = (const float*)d_in[1];
  const int* labels = (const int*)d_in[2];
  float* out = (float*)d_out;
  char* ws = (char*)d_ws;

  // workspace layout (bytes)
  __hip_bfloat16* img_nb = (__hip_bfloat16*)(ws);             //  6,291,456
  __hip_bfloat16* txt_nb = (__hip_bfloat16*)(ws + 6291456);   //  6,291,456
  float* row_part = (float*)(ws + 12582912);                  //    262,144 (16 x 4096)
  float* col_part = (float*)(ws + 12845056);                  //    262,144
  float* S_part = (float*)(ws + 13107200);                    //      1,024
  double* accs = (double*)(ws + 13108224);                    //  16 (+cnt 4)
  unsigned* cnt = (unsigned*)(ws + 13108240);

  normalize_kernel<<<2 * N_, 192, 0, stream>>>(img, txt, img_nb, txt_nb, accs, cnt);
  gemm_epi_kernel<<<dim3(16, 16), 512, 0, stream>>>(
      (const unsigned short*)img_nb, (const unsigned short*)txt_nb, labels,
      row_part, col_part, S_part);
  reduce_kernel<<<16, 256, 0, stream>>>(row_part, col_part, S_part, labels, accs, cnt, out);
}